// Round 1
// baseline (1992.034 us; speedup 1.0000x reference)
//
#include <hip/hip_runtime.h>
#include <math.h>

// Problem constants (B,H,L,DK = 2,16,2048,128; S = L)
#define B_  2
#define H_  16
#define L_  2048
#define S_  2048
#define D_  128
#define BM  32            // query rows per block
#define BN  32            // keys per tile
#define NT  (S_ / BN)     // 64 key tiles (NO causal skip: masked logits are exactly -50
                          // per the reference's clamp-after-mask, and they participate
                          // in the softmax. Processing all tiles is exactly faithful.)
#define LDP (D_ + 4)      // +4 float pad keeps float4 alignment, breaks pow2 bank stride

__device__ __forceinline__ void fma4(float4& a, const float4& x, const float4& y) {
    a.x = fmaf(x.x, y.x, a.x);
    a.y = fmaf(x.y, y.y, a.y);
    a.z = fmaf(x.z, y.z, a.z);
    a.w = fmaf(x.w, y.w, a.w);
}

__global__ __launch_bounds__(256, 2)
void attn_fwd(const float* __restrict__ Q, const float* __restrict__ K,
              const float* __restrict__ V, float* __restrict__ Out) {
    const int qt = blockIdx.x;              // 0..63   query tile
    const int bh = blockIdx.y;              // 0..31   (b*H + h)
    const long base = (long)bh * (L_ * D_);
    const int t = threadIdx.x;

    __shared__ float Qs[BM][LDP];
    __shared__ float Ks[BN][LDP];
    __shared__ float Vs[BN][LDP];
    __shared__ float Ps[BM][BN + 1];        // probs tile (LDS round-trip to PV mapping)
    __shared__ float mS[BM], lS[BM], aS[BM];

    // ---- load Q tile (32x128 fp32 = 1024 float4, 4 per thread, coalesced) ----
    {
        const float4* Qg = (const float4*)(Q + base + (long)qt * (BM * D_));
        #pragma unroll
        for (int rep = 0; rep < 4; ++rep) {
            int e = rep * 256 + t;          // float4 index within tile
            int r = e >> 5;                 // 32 float4 per row
            int c = (e & 31) << 2;
            *(float4*)&Qs[r][c] = Qg[e];
        }
    }
    if (t < BM) { mS[t] = -1e30f; lS[t] = 0.0f; }

    // ---- per-thread mappings ----
    // PV / output phase: 8 threads per row, 16 contiguous cols each
    const int ro = t >> 3;                  // 0..31
    const int co = (t & 7) << 4;            // 0,16,...,112
    // score phase: 16-lane groups own rows {sr, sr+16}, cols {sc, sc+16}
    const int sr = t >> 4;                  // 0..15
    const int sc = t & 15;                  // 0..15
    const int qr0 = qt * BM + sr;
    const int qr1 = qr0 + 16;
    const float scale = 0.08838834764831845f;   // 1/sqrt(128)

    float4 o0 = {0,0,0,0}, o1 = {0,0,0,0}, o2 = {0,0,0,0}, o3 = {0,0,0,0};

    for (int j = 0; j < NT; ++j) {
        __syncthreads();   // previous PV phase done reading Ks/Vs/Ps
        // ---- stage K,V tiles ----
        {
            const float4* Kg = (const float4*)(K + base + (long)j * (BN * D_));
            const float4* Vg = (const float4*)(V + base + (long)j * (BN * D_));
            #pragma unroll
            for (int rep = 0; rep < 4; ++rep) {
                int e = rep * 256 + t;
                int r = e >> 5;
                int c = (e & 31) << 2;
                *(float4*)&Ks[r][c] = Kg[e];
                *(float4*)&Vs[r][c] = Vg[e];
            }
        }
        __syncthreads();

        // ---- scores: 2x2 register block, float4 LDS reads ----
        float4 a00 = {0,0,0,0}, a01 = {0,0,0,0}, a10 = {0,0,0,0}, a11 = {0,0,0,0};
        #pragma unroll 4
        for (int d = 0; d < D_; d += 4) {
            float4 q0 = *(const float4*)&Qs[sr][d];
            float4 q1 = *(const float4*)&Qs[sr + 16][d];
            float4 k0 = *(const float4*)&Ks[sc][d];
            float4 k1 = *(const float4*)&Ks[sc + 16][d];
            fma4(a00, q0, k0);
            fma4(a01, q0, k1);
            fma4(a10, q1, k0);
            fma4(a11, q1, k1);
        }
        float s00 = (a00.x + a00.y) + (a00.z + a00.w);
        float s01 = (a01.x + a01.y) + (a01.z + a01.w);
        float s10 = (a10.x + a10.y) + (a10.z + a10.w);
        float s11 = (a11.x + a11.y) + (a11.z + a11.w);
        const int cs0 = j * BN + sc;
        const int cs1 = cs0 + 16;
        s00 *= scale; s01 *= scale; s10 *= scale; s11 *= scale;
        // mask -> -inf, then clamp(-50,50)  ==  masked = -50, valid clamped
        s00 = (cs0 > qr0) ? -50.0f : fminf(fmaxf(s00, -50.0f), 50.0f);
        s01 = (cs1 > qr0) ? -50.0f : fminf(fmaxf(s01, -50.0f), 50.0f);
        s10 = (cs0 > qr1) ? -50.0f : fminf(fmaxf(s10, -50.0f), 50.0f);
        s11 = (cs1 > qr1) ? -50.0f : fminf(fmaxf(s11, -50.0f), 50.0f);

        // ---- online softmax: reduce across the 16 lanes owning this row ----
        float tm0 = fmaxf(s00, s01);
        float tm1 = fmaxf(s10, s11);
        #pragma unroll
        for (int off = 1; off < 16; off <<= 1) {
            tm0 = fmaxf(tm0, __shfl_xor(tm0, off));
            tm1 = fmaxf(tm1, __shfl_xor(tm1, off));
        }
        float m0_old = mS[sr], m1_old = mS[sr + 16];
        float m0 = fmaxf(m0_old, tm0);
        float m1 = fmaxf(m1_old, tm1);
        float p00 = __expf(s00 - m0), p01 = __expf(s01 - m0);
        float p10 = __expf(s10 - m1), p11 = __expf(s11 - m1);
        float ts0 = p00 + p01, ts1 = p10 + p11;
        #pragma unroll
        for (int off = 1; off < 16; off <<= 1) {
            ts0 += __shfl_xor(ts0, off);
            ts1 += __shfl_xor(ts1, off);
        }
        if (sc == 0) {
            float al0 = __expf(m0_old - m0);
            float al1 = __expf(m1_old - m1);
            mS[sr]      = m0;
            mS[sr + 16] = m1;
            lS[sr]      = lS[sr]      * al0 + ts0;
            lS[sr + 16] = lS[sr + 16] * al1 + ts1;
            aS[sr]      = al0;
            aS[sr + 16] = al1;
        }
        Ps[sr][sc]           = p00;
        Ps[sr][sc + 16]      = p01;
        Ps[sr + 16][sc]      = p10;
        Ps[sr + 16][sc + 16] = p11;
        __syncthreads();

        // ---- PV accumulate: O = O*alpha + P @ V ----
        float alpha = aS[ro];
        o0.x *= alpha; o0.y *= alpha; o0.z *= alpha; o0.w *= alpha;
        o1.x *= alpha; o1.y *= alpha; o1.z *= alpha; o1.w *= alpha;
        o2.x *= alpha; o2.y *= alpha; o2.z *= alpha; o2.w *= alpha;
        o3.x *= alpha; o3.y *= alpha; o3.z *= alpha; o3.w *= alpha;
        #pragma unroll 4
        for (int s = 0; s < BN; ++s) {
            float p = Ps[ro][s];
            float4 v0 = *(const float4*)&Vs[s][co];
            float4 v1 = *(const float4*)&Vs[s][co + 4];
            float4 v2 = *(const float4*)&Vs[s][co + 8];
            float4 v3 = *(const float4*)&Vs[s][co + 12];
            o0.x = fmaf(p, v0.x, o0.x); o0.y = fmaf(p, v0.y, o0.y);
            o0.z = fmaf(p, v0.z, o0.z); o0.w = fmaf(p, v0.w, o0.w);
            o1.x = fmaf(p, v1.x, o1.x); o1.y = fmaf(p, v1.y, o1.y);
            o1.z = fmaf(p, v1.z, o1.z); o1.w = fmaf(p, v1.w, o1.w);
            o2.x = fmaf(p, v2.x, o2.x); o2.y = fmaf(p, v2.y, o2.y);
            o2.z = fmaf(p, v2.z, o2.z); o2.w = fmaf(p, v2.w, o2.w);
            o3.x = fmaf(p, v3.x, o3.x); o3.y = fmaf(p, v3.y, o3.y);
            o3.z = fmaf(p, v3.z, o3.z); o3.w = fmaf(p, v3.w, o3.w);
        }
    }

    __syncthreads();
    const float linv = 1.0f / lS[ro];
    o0.x *= linv; o0.y *= linv; o0.z *= linv; o0.w *= linv;
    o1.x *= linv; o1.y *= linv; o1.z *= linv; o1.w *= linv;
    o2.x *= linv; o2.y *= linv; o2.z *= linv; o2.w *= linv;
    o3.x *= linv; o3.y *= linv; o3.z *= linv; o3.w *= linv;
    float* Og = Out + base + (long)(qt * BM + ro) * D_ + co;
    *(float4*)&Og[0]  = o0;
    *(float4*)&Og[4]  = o1;
    *(float4*)&Og[8]  = o2;
    *(float4*)&Og[12] = o3;
}

extern "C" void kernel_launch(void* const* d_in, const int* in_sizes, int n_in,
                              void* d_out, int out_size, void* d_ws, size_t ws_size,
                              hipStream_t stream) {
    const float* Q = (const float*)d_in[0];
    const float* K = (const float*)d_in[1];
    const float* V = (const float*)d_in[2];
    float* O = (float*)d_out;
    dim3 grid(L_ / BM, B_ * H_);   // x = q-tile (same bh adjacent -> K/V L2 reuse)
    attn_fwd<<<grid, dim3(256), 0, stream>>>(Q, K, V, O);
}

// Round 2
// 244.450 us; speedup vs baseline: 8.1490x; 8.1490x over previous
//
#include <hip/hip_runtime.h>
#include <math.h>

// B,H,L,DK = 2,16,2048,128 ; S=L. Inputs fp32, output fp32.
#define BH_ 32
#define L_  2048
#define D_  128
#define BM  64            // Q rows per block
#define BN  64            // keys per tile
#define QLD 136           // LDS row stride (bf16 elems) for Q/K tiles: 272 B = 17*16 -> aligned b128, 2-way-free banks
#define VLD 72            // LDS row stride for Vt tile: 144 B = 9*16
#define PLD 72            // LDS row stride for P slab

typedef __attribute__((ext_vector_type(8))) __bf16 bf16x8;
typedef __attribute__((ext_vector_type(4))) float  f32x4;

__device__ __forceinline__ unsigned short f2bf(float x) {
    union { float f; unsigned u; } v; v.f = x;
    return (unsigned short)((v.u + 0x7FFFu + ((v.u >> 16) & 1u)) >> 16);   // RTNE
}

// ---------------- prepass: K -> bf16 (row-major), V -> bf16 transposed [bh][d][s] ----------------
__global__ __launch_bounds__(256)
void prepack(const float* __restrict__ K, const float* __restrict__ V,
             unsigned short* __restrict__ Kb, unsigned short* __restrict__ Vt) {
    const int bh = blockIdx.x;          // 0..31
    const int st = blockIdx.y;          // 0..31  (64 s-rows each)
    const int t  = threadIdx.x;
    __shared__ unsigned short buf[64 * 132];   // V tile bf16, pad +4

    const long inb = (long)(bh * L_ + st * 64) * D_;
    const float4* Kg = (const float4*)(K + inb);
    const float4* Vg = (const float4*)(V + inb);
    ushort4* Ko = (ushort4*)(Kb + inb);

    #pragma unroll
    for (int rep = 0; rep < 8; ++rep) {
        int e = rep * 256 + t;                  // 2048 float4 chunks
        float4 kx = Kg[e];
        ushort4 ky; ky.x = f2bf(kx.x); ky.y = f2bf(kx.y); ky.z = f2bf(kx.z); ky.w = f2bf(kx.w);
        Ko[e] = ky;
        float4 vx = Vg[e];
        ushort4 vy; vy.x = f2bf(vx.x); vy.y = f2bf(vx.y); vy.z = f2bf(vx.z); vy.w = f2bf(vx.w);
        int row = e >> 5, col = (e & 31) * 4;
        *(ushort4*)&buf[row * 132 + col] = vy;
    }
    __syncthreads();

    unsigned short* Vo = Vt + (long)bh * D_ * L_ + st * 64;
    #pragma unroll
    for (int rep = 0; rep < 4; ++rep) {
        int c = rep * 256 + t;                  // 1024 out-chunks of 8
        int d = c >> 3, s0 = (c & 7) * 8;
        union { unsigned short us[8]; uint4 v; } pk;
        #pragma unroll
        for (int i = 0; i < 8; ++i) pk.us[i] = buf[(s0 + i) * 132 + d];
        *(uint4*)(Vo + (long)d * L_ + s0) = pk.v;
    }
}

// ---------------- main flash-attention kernel (bf16 MFMA) ----------------
__global__ __launch_bounds__(256, 2)
void attn(const float* __restrict__ Q, const unsigned short* __restrict__ Kb,
          const unsigned short* __restrict__ Vt, float* __restrict__ Out) {
    const int bh   = blockIdx.x;
    const int qt   = (int)gridDim.y - 1 - (int)blockIdx.y;   // big q-tiles dispatch first
    const int t    = threadIdx.x;
    const int w    = t >> 6;
    const int lane = t & 63;
    const int quad = lane >> 4;
    const int m16  = lane & 15;

    __shared__ unsigned short Qs[BM * QLD];     // 17408 B
    __shared__ unsigned short Ks[BN * QLD];     // 17408 B
    __shared__ unsigned short Vs[D_ * VLD];     // 18432 B  (Vt tile: [d][s])
    __shared__ unsigned short Ps[4 * 16 * PLD]; //  9216 B  (wave-private P slabs)

    const long qbase = (long)(bh * L_ + qt * BM) * D_;

    // ---- stage Q (fp32 -> bf16), once ----
    {
        const float4* Qg = (const float4*)(Q + qbase);
        #pragma unroll
        for (int rep = 0; rep < 8; ++rep) {
            int e = rep * 256 + t;
            int row = e >> 5, col = (e & 31) * 4;
            float4 x = Qg[e];
            ushort4 y; y.x = f2bf(x.x); y.y = f2bf(x.y); y.z = f2bf(x.z); y.w = f2bf(x.w);
            *(ushort4*)&Qs[row * QLD + col] = y;
        }
    }
    __syncthreads();

    bf16x8 qf[4];
    #pragma unroll
    for (int ks = 0; ks < 4; ++ks)
        qf[ks] = *(const bf16x8*)&Qs[(w * 16 + m16) * QLD + ks * 32 + quad * 8];

    f32x4 o[8];
    #pragma unroll
    for (int nt = 0; nt < 8; ++nt) o[nt] = (f32x4){0.f, 0.f, 0.f, 0.f};
    float m_[4], l_[4];
    #pragma unroll
    for (int r = 0; r < 4; ++r) { m_[r] = -1e30f; l_[r] = 0.f; }

    const int   qrow0 = qt * BM + w * 16 + quad * 4;           // + r
    const float scale = 0.08838834764831845f;                  // 1/sqrt(128)
    const float LOG2E = 1.4426950408889634f;
    unsigned short* Pw = &Ps[w * 16 * PLD];

    const uint4* Kt0 = (const uint4*)(Kb + (long)bh * L_ * D_);
    const uint4* Vt0 = (const uint4*)(Vt + (long)bh * D_ * L_);

    for (int j = 0; j <= qt; ++j) {            // causal skip: tiles above diagonal contribute <1e-17
        __syncthreads();
        // ---- stage K tile (bf16, straight) + V tile (bf16, pre-transposed) ----
        {
            const uint4* Kg4 = Kt0 + (long)j * (BN * D_ / 8);
            #pragma unroll
            for (int rep = 0; rep < 4; ++rep) {
                int c = rep * 256 + t;
                int row = c >> 4, col = (c & 15) * 8;
                *(uint4*)&Ks[row * QLD + col] = Kg4[c];
            }
            #pragma unroll
            for (int rep = 0; rep < 4; ++rep) {
                int c = rep * 256 + t;
                int d = c >> 3, cc = c & 7;
                *(uint4*)&Vs[d * VLD + cc * 8] = Vt0[(long)d * (L_ / 8) + j * 8 + cc];
            }
        }
        __syncthreads();

        // ---- scores: S = Q K^T, wave slab = 16 rows x 64 cols ----
        f32x4 acc[4];
        #pragma unroll
        for (int nt = 0; nt < 4; ++nt) {
            acc[nt] = (f32x4){0.f, 0.f, 0.f, 0.f};
            #pragma unroll
            for (int ks = 0; ks < 4; ++ks) {
                bf16x8 kf = *(const bf16x8*)&Ks[(nt * 16 + m16) * QLD + ks * 32 + quad * 8];
                acc[nt] = __builtin_amdgcn_mfma_f32_16x16x32_bf16(qf[ks], kf, acc[nt], 0, 0, 0);
            }
        }

        // ---- mask + clamp + online softmax (register state, shuffle reductions) ----
        float p[4][4];                         // [nt][r]
        float tm[4];
        const bool diag = (j == qt);
        #pragma unroll
        for (int r = 0; r < 4; ++r) tm[r] = -1e30f;
        #pragma unroll
        for (int nt = 0; nt < 4; ++nt) {
            int colc = j * BN + nt * 16 + m16;
            #pragma unroll
            for (int r = 0; r < 4; ++r) {
                float v = acc[nt][r] * scale;
                v = fminf(fmaxf(v, -50.f), 50.f);           // clamp (after-mask semantics: masked=-50)
                if (diag && colc > qrow0 + r) v = -50.f;
                p[nt][r] = v;
                tm[r] = fmaxf(tm[r], v);
            }
        }
        #pragma unroll
        for (int off = 1; off < 16; off <<= 1) {
            #pragma unroll
            for (int r = 0; r < 4; ++r) tm[r] = fmaxf(tm[r], __shfl_xor(tm[r], off));
        }
        float alpha[4], rs[4];
        #pragma unroll
        for (int r = 0; r < 4; ++r) {
            float mn = fmaxf(m_[r], tm[r]);
            alpha[r] = exp2f((m_[r] - mn) * LOG2E);
            m_[r] = mn;
            rs[r] = 0.f;
        }
        #pragma unroll
        for (int nt = 0; nt < 4; ++nt) {
            #pragma unroll
            for (int r = 0; r < 4; ++r) {
                float e = exp2f((p[nt][r] - m_[r]) * LOG2E);
                p[nt][r] = e;
                rs[r] += e;
            }
        }
        #pragma unroll
        for (int off = 1; off < 16; off <<= 1) {
            #pragma unroll
            for (int r = 0; r < 4; ++r) rs[r] += __shfl_xor(rs[r], off);
        }
        #pragma unroll
        for (int r = 0; r < 4; ++r) l_[r] = l_[r] * alpha[r] + rs[r];

        // ---- rescale O accumulators by alpha (rows match C-layout reg index) ----
        #pragma unroll
        for (int nt = 0; nt < 8; ++nt) {
            #pragma unroll
            for (int r = 0; r < 4; ++r) o[nt][r] *= alpha[r];
        }

        // ---- P: C-layout regs -> LDS -> A-operand layout (wave-private slab) ----
        #pragma unroll
        for (int nt = 0; nt < 4; ++nt) {
            #pragma unroll
            for (int r = 0; r < 4; ++r)
                Pw[(quad * 4 + r) * PLD + nt * 16 + m16] = f2bf(p[nt][r]);
        }
        __syncthreads();

        // ---- O += P V  (B-frags from pre-transposed V tile) ----
        #pragma unroll
        for (int ks = 0; ks < 2; ++ks) {
            bf16x8 pf = *(const bf16x8*)&Pw[m16 * PLD + ks * 32 + quad * 8];
            #pragma unroll
            for (int nt = 0; nt < 8; ++nt) {
                bf16x8 vf = *(const bf16x8*)&Vs[(nt * 16 + m16) * VLD + ks * 32 + quad * 8];
                o[nt] = __builtin_amdgcn_mfma_f32_16x16x32_bf16(pf, vf, o[nt], 0, 0, 0);
            }
        }
    }

    // ---- epilogue: O / l ----
    float linv[4];
    #pragma unroll
    for (int r = 0; r < 4; ++r) linv[r] = 1.f / l_[r];
    float* Og = Out + qbase;
    #pragma unroll
    for (int nt = 0; nt < 8; ++nt) {
        #pragma unroll
        for (int r = 0; r < 4; ++r)
            Og[(w * 16 + quad * 4 + r) * D_ + nt * 16 + m16] = o[nt][r] * linv[r];
    }
}

extern "C" void kernel_launch(void* const* d_in, const int* in_sizes, int n_in,
                              void* d_out, int out_size, void* d_ws, size_t ws_size,
                              hipStream_t stream) {
    const float* Q = (const float*)d_in[0];
    const float* K = (const float*)d_in[1];
    const float* V = (const float*)d_in[2];
    float* O = (float*)d_out;
    unsigned short* Kb = (unsigned short*)d_ws;                          // 16 MiB
    unsigned short* Vt = Kb + (long)BH_ * L_ * D_;                       // 16 MiB
    prepack<<<dim3(BH_, L_ / 64), dim3(256), 0, stream>>>(K, V, Kb, Vt);
    attn<<<dim3(BH_, L_ / BM), dim3(256), 0, stream>>>(Q, Kb, Vt, O);
}

// Round 3
// 224.079 us; speedup vs baseline: 8.8899x; 1.0909x over previous
//
#include <hip/hip_runtime.h>
#include <math.h>

// B,H,L,DK = 2,16,2048,128 ; S=L. Inputs fp32, output fp32.
#define BH_ 32
#define L_  2048
#define D_  128
#define BM  128           // Q rows per block (4 waves x 32 rows)
#define BN  64            // keys per tile
#define NQT (L_ / BM)     // 16 q-tiles

typedef __attribute__((ext_vector_type(8)))  __bf16 bf16x8;
typedef __attribute__((ext_vector_type(16))) float  f32x16;

__device__ __forceinline__ unsigned short f2bf(float x) {
    union { float f; unsigned u; } v; v.f = x;
    return (unsigned short)((v.u + 0x7FFFu + ((v.u >> 16) & 1u)) >> 16);   // RTNE
}

// async 16B/lane global->LDS (LDS dest = wave-uniform base + lane*16)
__device__ __forceinline__ void gload_lds16(const void* g, void* l) {
    __builtin_amdgcn_global_load_lds(
        (const __attribute__((address_space(1))) unsigned int*)g,
        (__attribute__((address_space(3))) unsigned int*)l, 16, 0, 0);
}

// ---------------- prepass: K -> bf16 row-major, V -> bf16 transposed [bh][d][s] ----------------
__global__ __launch_bounds__(256)
void prepack(const float* __restrict__ K, const float* __restrict__ V,
             unsigned short* __restrict__ Kb, unsigned short* __restrict__ Vt) {
    const int bh = blockIdx.x;          // 0..31
    const int st = blockIdx.y;          // 0..31  (64 s-rows each)
    const int t  = threadIdx.x;
    __shared__ unsigned short buf[64 * 132];   // V tile bf16, pad +4

    const long inb = (long)(bh * L_ + st * 64) * D_;
    const float4* Kg = (const float4*)(K + inb);
    const float4* Vg = (const float4*)(V + inb);
    ushort4* Ko = (ushort4*)(Kb + inb);

    #pragma unroll
    for (int rep = 0; rep < 8; ++rep) {
        int e = rep * 256 + t;                  // 2048 float4 chunks
        float4 kx = Kg[e];
        ushort4 ky; ky.x = f2bf(kx.x); ky.y = f2bf(kx.y); ky.z = f2bf(kx.z); ky.w = f2bf(kx.w);
        Ko[e] = ky;
        float4 vx = Vg[e];
        ushort4 vy; vy.x = f2bf(vx.x); vy.y = f2bf(vx.y); vy.z = f2bf(vx.z); vy.w = f2bf(vx.w);
        int row = e >> 5, col = (e & 31) * 4;
        *(ushort4*)&buf[row * 132 + col] = vy;
    }
    __syncthreads();

    unsigned short* Vo = Vt + (long)bh * D_ * L_ + st * 64;
    #pragma unroll
    for (int rep = 0; rep < 4; ++rep) {
        int c = rep * 256 + t;                  // 1024 out-chunks of 8
        int d = c >> 3, s0 = (c & 7) * 8;
        union { unsigned short us[8]; uint4 v; } pk;
        #pragma unroll
        for (int i = 0; i < 8; ++i) pk.us[i] = buf[(s0 + i) * 132 + d];
        *(uint4*)(Vo + (long)d * L_ + s0) = pk.v;
    }
}

// ---------------- main kernel: 32x32x16 MFMA, static-max softmax, async staging ----------------
// LDS map (49152 B): Ks[s=64][256B] @0, Vs[d=128][128B] @16384, P slabs 4x4096B @32768.
// All tiles XOR-granule swizzled: 16B granule slot = g ^ (row & (granules-1)).
__global__ __launch_bounds__(256, 2)
void attn(const float* __restrict__ Q, const unsigned short* __restrict__ Kb,
          const unsigned short* __restrict__ Vt, float* __restrict__ Out) {
    __shared__ __align__(16) char smem[49152];
    char* const KsB = smem;
    char* const VsB = smem + 16384;

    const int bh = blockIdx.x;
    const int yy = blockIdx.y;
    // pair-balanced qt order: 15,0,14,1,... so co-resident block pairs have ~equal work
    const int qt = (yy & 1) ? (yy >> 1) : (NQT - 1 - (yy >> 1));
    const int t = threadIdx.x;
    const int w = t >> 6, lane = t & 63;
    const int half = lane >> 5, l32 = lane & 31;
    char* const Pw = smem + 32768 + w * 4096;   // wave-private P slab: [m=32][128B]

    const long qbase = ((long)bh * L_ + (long)qt * BM) * D_;

    // ---- stage Q fp32 -> bf16 swizzled into smem[0:32768) (overlays Ks+Vs) ----
    {
        const float4* Qg = (const float4*)(Q + qbase);
        #pragma unroll
        for (int rep = 0; rep < 16; ++rep) {
            int e = rep * 256 + t;              // 4096 float4 = 128x128
            int m = e >> 5;
            int d0 = (e & 31) << 2;
            float4 x = Qg[e];
            ushort4 y;
            y.x = f2bf(x.x); y.y = f2bf(x.y); y.z = f2bf(x.z); y.w = f2bf(x.w);
            *(ushort4*)(smem + m * 256 + (((d0 >> 3) ^ (m & 15)) << 4) + ((d0 & 7) << 1)) = y;
        }
    }
    __syncthreads();

    // ---- Q A-frags to registers (32 VGPR), rows w*32..w*32+31 ----
    bf16x8 qf[8];
    {
        const int qm = w * 32 + l32;
        #pragma unroll
        for (int ks = 0; ks < 8; ++ks) {
            int g = ks * 2 + half;
            qf[ks] = *(const bf16x8*)(smem + qm * 256 + ((g ^ (qm & 15)) << 4));
        }
    }

    f32x16 o[4], lac;
    #pragma unroll
    for (int cb = 0; cb < 4; ++cb)
        #pragma unroll
        for (int r = 0; r < 16; ++r) o[cb][r] = 0.f;
    #pragma unroll
    for (int r = 0; r < 16; ++r) lac[r] = 0.f;

    bf16x8 onesf;
    #pragma unroll
    for (int i = 0; i < 8; ++i) onesf[i] = (__bf16)1.0f;

    const char* const KbB = (const char*)Kb + (long)bh * (L_ * D_ * 2);
    const char* const VtB = (const char*)Vt + (long)bh * (D_ * L_ * 2);
    const int jmax  = 2 * qt + 1;
    const int rowg0 = qt * BM + w * 32 + 4 * half;   // + (r&3) + 8*(r>>2)
    const int wlim  = qt * BM + w * 32 + 31;         // wave's last row (global)

    for (int j = 0; j <= jmax; ++j) {
        __syncthreads();   // prev tile fully consumed; also guards Q-frag reads (j==0)
        // ---- async stage K tile: wave w stages rows w*16..w*16+15 (4 chunks x 4 rows) ----
        #pragma unroll
        for (int cc = 0; cc < 4; ++cc) {
            const int c  = w * 4 + cc;
            const int sl = c * 4 + (lane >> 4);
            const int g  = (lane & 15) ^ (sl & 15);
            gload_lds16(KbB + (long)(j * 64 + sl) * 256 + (g << 4), KsB + c * 1024);
        }
        // ---- async stage V tile (pre-transposed): wave w stages d-rows w*32..+31 ----
        #pragma unroll
        for (int cc = 0; cc < 4; ++cc) {
            const int c  = w * 4 + cc;
            const int dl = c * 8 + (lane >> 3);
            const int g  = (lane & 7) ^ (dl & 7);
            gload_lds16(VtB + (long)dl * (L_ * 2) + j * 128 + (g << 4), VsB + c * 1024);
        }
        __syncthreads();   // compiler drains vmcnt before barrier -> tiles ready

        if (j * 64 <= wlim) {                  // skip fully-masked wave-tiles (exact: P would be 0)
            // ---- scores: S = Q K^T (32 rows x 64 cols per wave) ----
            f32x16 acc[2];
            #pragma unroll
            for (int cb = 0; cb < 2; ++cb)
                #pragma unroll
                for (int r = 0; r < 16; ++r) acc[cb][r] = 0.f;
            #pragma unroll
            for (int cb = 0; cb < 2; ++cb) {
                const int srow = cb * 32 + l32;
                const char* kbase = KsB + srow * 256;
                const int sw = srow & 15;
                #pragma unroll
                for (int ks = 0; ks < 8; ++ks) {
                    bf16x8 kf = *(const bf16x8*)(kbase + (((ks * 2 + half) ^ sw) << 4));
                    acc[cb] = __builtin_amdgcn_mfma_f32_32x32x16_bf16(qf[ks], kf, acc[cb], 0, 0, 0);
                }
            }

            // ---- static-max softmax: p = exp(clamp(s)-50); masked -> exp(-100) = 0 ----
            const bool need_mask = (j >= 2 * qt);
            #pragma unroll
            for (int cb = 0; cb < 2; ++cb) {
                const int colg = j * 64 + cb * 32 + l32;
                const int sP   = cb * 32 + l32;
                #pragma unroll
                for (int r = 0; r < 16; ++r) {
                    float v = acc[cb][r] * 0.08838834764831845f;
                    v = fminf(fmaxf(v, -50.f), 50.f);
                    if (need_mask && colg > rowg0 + (r & 3) + 8 * (r >> 2)) v = -50.f;
                    float p = exp2f(fmaf(v, 1.4426950408889634f, -72.134752044448170f));
                    const int m = (r & 3) + 8 * (r >> 2) + 4 * half;
                    *(unsigned short*)(Pw + m * 128 + ((((sP >> 3) ^ (m & 7)) << 4)) + ((sP & 7) << 1)) = f2bf(p);
                }
            }

            // ---- O += P V ; l += P . 1 (ones B-frag reuses P A-frags; D-layout matches O) ----
            #pragma unroll
            for (int ks = 0; ks < 4; ++ks) {
                const int g = ks * 2 + half;
                bf16x8 pf = *(const bf16x8*)(Pw + l32 * 128 + ((g ^ (l32 & 7)) << 4));
                #pragma unroll
                for (int cb = 0; cb < 4; ++cb) {
                    const int d = cb * 32 + l32;
                    bf16x8 vf = *(const bf16x8*)(VsB + d * 128 + ((g ^ (d & 7)) << 4));
                    o[cb] = __builtin_amdgcn_mfma_f32_32x32x16_bf16(pf, vf, o[cb], 0, 0, 0);
                }
                lac = __builtin_amdgcn_mfma_f32_32x32x16_bf16(pf, onesf, lac, 0, 0, 0);
            }
        }
    }

    // ---- epilogue: O / l  (l D-regs share O's row mapping -> no cross-lane) ----
    float* Og = Out + qbase;
    #pragma unroll
    for (int r = 0; r < 16; ++r) {
        const float linv = 1.0f / lac[r];
        const long rowl = w * 32 + (r & 3) + 8 * (r >> 2) + 4 * half;
        #pragma unroll
        for (int cb = 0; cb < 4; ++cb)
            Og[rowl * D_ + cb * 32 + l32] = o[cb][r] * linv;
    }
}

extern "C" void kernel_launch(void* const* d_in, const int* in_sizes, int n_in,
                              void* d_out, int out_size, void* d_ws, size_t ws_size,
                              hipStream_t stream) {
    const float* Q = (const float*)d_in[0];
    const float* K = (const float*)d_in[1];
    const float* V = (const float*)d_in[2];
    float* O = (float*)d_out;
    unsigned short* Kb = (unsigned short*)d_ws;                          // 16 MiB
    unsigned short* Vt = Kb + (long)BH_ * L_ * D_;                       // 16 MiB
    prepack<<<dim3(BH_, L_ / 64), dim3(256), 0, stream>>>(K, V, Kb, Vt);
    attn<<<dim3(BH_, NQT), dim3(256), 0, stream>>>(Q, Kb, Vt, O);
}

// Round 4
// 216.791 us; speedup vs baseline: 9.1887x; 1.0336x over previous
//
#include <hip/hip_runtime.h>
#include <math.h>

// B,H,L,DK = 2,16,2048,128 ; S=L. Inputs fp32, output fp32.
#define BH_ 32
#define L_  2048
#define D_  128
#define BM  128           // Q rows per block (4 waves x 32 rows)
#define NQT (L_ / BM)     // 16 q-tiles

typedef __attribute__((ext_vector_type(8)))  __bf16 bf16x8;
typedef __attribute__((ext_vector_type(16))) float  f32x16;

__device__ __forceinline__ unsigned short f2bf(float x) {
    union { float f; unsigned u; } v; v.f = x;
    return (unsigned short)((v.u + 0x7FFFu + ((v.u >> 16) & 1u)) >> 16);   // RTNE
}

// async 16B/lane global->LDS (LDS dest = wave-uniform base + lane*16)
__device__ __forceinline__ void gload_lds16(const void* g, void* l) {
    __builtin_amdgcn_global_load_lds(
        (const __attribute__((address_space(1))) unsigned int*)g,
        (__attribute__((address_space(3))) unsigned int*)l, 16, 0, 0);
}

// ---------------- prepass: K -> bf16 row-major, V -> bf16 transposed [bh][d][s] ----------------
// V transpose via s-pair-packed uints: phase1 writes b128 rows [sp][d], phase2 reads 4x b32 per out.
__global__ __launch_bounds__(256)
void prepack(const float* __restrict__ K, const float* __restrict__ V,
             unsigned short* __restrict__ Kb, unsigned short* __restrict__ Vt) {
    const int bh = blockIdx.x, st = blockIdx.y, t = threadIdx.x;
    __shared__ unsigned int lbuf[32 * 132];     // [sp=32][128 d + pad 4] uints
    const long inb = ((long)bh * L_ + st * 64) * D_;
    const float4* Kg = (const float4*)(K + inb);
    const float4* Vg = (const float4*)(V + inb);
    ushort4* Ko = (ushort4*)(Kb + inb);

    #pragma unroll
    for (int rep = 0; rep < 4; ++rep) {
        int e = rep * 256 + t;                  // 1024 pair-chunks
        int sp = e >> 5, c4 = e & 31;           // s-pair, d-quad
        int r0 = sp * 2;
        float4 k0 = Kg[r0 * 32 + c4], k1 = Kg[(r0 + 1) * 32 + c4];
        ushort4 ka; ka.x = f2bf(k0.x); ka.y = f2bf(k0.y); ka.z = f2bf(k0.z); ka.w = f2bf(k0.w);
        ushort4 kc; kc.x = f2bf(k1.x); kc.y = f2bf(k1.y); kc.z = f2bf(k1.z); kc.w = f2bf(k1.w);
        Ko[r0 * 32 + c4] = ka;
        Ko[(r0 + 1) * 32 + c4] = kc;
        float4 v0 = Vg[r0 * 32 + c4], v1 = Vg[(r0 + 1) * 32 + c4];
        uint4 pk;
        pk.x = (unsigned)f2bf(v0.x) | ((unsigned)f2bf(v1.x) << 16);
        pk.y = (unsigned)f2bf(v0.y) | ((unsigned)f2bf(v1.y) << 16);
        pk.z = (unsigned)f2bf(v0.z) | ((unsigned)f2bf(v1.z) << 16);
        pk.w = (unsigned)f2bf(v0.w) | ((unsigned)f2bf(v1.w) << 16);
        *(uint4*)&lbuf[sp * 132 + c4 * 4] = pk;
    }
    __syncthreads();

    unsigned short* Vo = Vt + (long)bh * D_ * L_ + st * 64;
    #pragma unroll
    for (int rep = 0; rep < 4; ++rep) {
        int c = rep * 256 + t;                  // 1024 outputs of 8 ushorts
        int d = c >> 3, q = c & 7;
        uint4 o4;
        o4.x = lbuf[(q * 4 + 0) * 132 + d];
        o4.y = lbuf[(q * 4 + 1) * 132 + d];
        o4.z = lbuf[(q * 4 + 2) * 132 + d];
        o4.w = lbuf[(q * 4 + 3) * 132 + d];
        *(uint4*)(Vo + (long)d * L_ + q * 8) = o4;      // s ascending: pairs are (2sp,2sp+1)
    }
}

// ---------------- main kernel: S^T/O^T form, double-buffered async staging, no P round-trip ----
// LDS 64KB: K0[0,16K) K1[16K,32K) V0[32K,48K) V1[48K,64K). Epilogue reuses [0,34816) for O transpose.
// K tile row: 256B, 16 granules, slot = g ^ (row&15). V tile row (d): 128B, 8 granules, slot = g ^ (d&7).
__global__ __launch_bounds__(256, 2)
void attn(const float* __restrict__ Q, const unsigned short* __restrict__ Kb,
          const unsigned short* __restrict__ Vt, float* __restrict__ Out) {
    __shared__ __align__(16) char smem[65536];

    const int bh = blockIdx.x;
    const int yy = blockIdx.y;
    const int qt = (yy & 1) ? (yy >> 1) : (NQT - 1 - (yy >> 1));   // pair-balanced work order
    const int t = threadIdx.x;
    const int w = t >> 6, lane = t & 63;
    const int half = lane >> 5, l32 = lane & 31;

    const long qbase = ((long)bh * L_ + (long)qt * BM) * D_;

    // ---- stage Q fp32->bf16 swizzled into smem[0,32K) (K0+K1 region, consumed before loop) ----
    {
        const float4* Qg = (const float4*)(Q + qbase);
        #pragma unroll
        for (int rep = 0; rep < 16; ++rep) {
            int e = rep * 256 + t;
            int m = e >> 5, d0 = (e & 31) << 2;
            float4 x = Qg[e];
            ushort4 y; y.x = f2bf(x.x); y.y = f2bf(x.y); y.z = f2bf(x.z); y.w = f2bf(x.w);
            *(ushort4*)(smem + m * 256 + (((d0 >> 3) ^ (m & 15)) << 4) + ((d0 & 7) << 1)) = y;
        }
    }
    __syncthreads();
    bf16x8 qf[8];                               // Q B-frags: lane n=m_q holds k contiguous
    {
        const int qm = w * 32 + l32;
        #pragma unroll
        for (int ks = 0; ks < 8; ++ks)
            qf[ks] = *(const bf16x8*)(smem + qm * 256 + (((ks * 2 + half) ^ (qm & 15)) << 4));
    }
    __syncthreads();                            // qf landed; safe to overwrite Q region

    f32x16 o[4];                                // O^T: reg r <-> d, lane l32 <-> m_q
    #pragma unroll
    for (int cb = 0; cb < 4; ++cb)
        #pragma unroll
        for (int r = 0; r < 16; ++r) o[cb][r] = 0.f;
    float l_ = 0.f;

    const char* const KbB = (const char*)Kb + (long)bh * (L_ * D_ * 2);
    const char* const VtB = (const char*)Vt + (long)bh * (D_ * L_ * 2);
    const int jmax = 2 * qt + 1;
    const int R0   = qt * BM + w * 32;          // wave's first q-row
    const int rowg = R0 + l32;                  // this lane's q-row
    const int wlim = R0 + 31;

    auto stage = [&](int j, int b) {
        char* Kd = smem + b * 16384;
        char* Vd = smem + 32768 + b * 16384;
        #pragma unroll
        for (int cc = 0; cc < 4; ++cc) {
            const int c  = w * 4 + cc;
            const int sl = c * 4 + (lane >> 4);
            const int g  = (lane & 15) ^ (sl & 15);
            gload_lds16(KbB + ((long)(j * 64 + sl) << 8) + (g << 4), Kd + c * 1024);
        }
        #pragma unroll
        for (int cc = 0; cc < 4; ++cc) {
            const int c  = w * 4 + cc;
            const int dl = c * 8 + (lane >> 3);
            const int g  = (lane & 7) ^ (dl & 7);
            gload_lds16(VtB + ((long)dl << 12) + (j << 7) + (g << 4), Vd + c * 1024);
        }
    };

    stage(0, 0);

    for (int j = 0; j <= jmax; ++j) {
        __syncthreads();                        // drains vmcnt: buf[j&1] ready; prev compute done
        if (j < jmax) stage(j + 1, (j + 1) & 1);// prefetch overlaps compute below
        if (j * 64 <= wlim) {
            const char* Kl = smem + (j & 1) * 16384;
            const char* Vl = smem + 32768 + (j & 1) * 16384;

            // ---- S^T = K Q^T : rows(regs)=s, col(lane)=m_q ----
            f32x16 acc[2];
            #pragma unroll
            for (int cb = 0; cb < 2; ++cb) {
                #pragma unroll
                for (int r = 0; r < 16; ++r) acc[cb][r] = 0.f;
                const int srow = cb * 32 + l32;
                const char* kb2 = Kl + srow * 256;
                const int sw = srow & 15;
                #pragma unroll
                for (int ks = 0; ks < 8; ++ks) {
                    bf16x8 kf = *(const bf16x8*)(kb2 + (((ks * 2 + half) ^ sw) << 4));
                    acc[cb] = __builtin_amdgcn_mfma_f32_32x32x16_bf16(kf, qf[ks], acc[cb], 0, 0, 0);
                }
            }

            // ---- static-max softmax (per-lane row!) + in-register P A/B-frag build ----
            bf16x8 pf[4];
            const bool nm = (j * 64 + 63 > R0);
            #pragma unroll
            for (int cb = 0; cb < 2; ++cb) {
                const int sb = j * 64 + cb * 32 + 4 * half;
                float pv[16];
                #pragma unroll
                for (int r = 0; r < 16; ++r) {
                    float v0 = acc[cb][r] * 0.12751743342187213f;   // scale*log2(e)
                    v0 = fminf(fmaxf(v0, -72.13475204444817f), 72.13475204444817f);
                    if (nm && (sb + ((r & 3) + 8 * (r >> 2)) > rowg)) v0 = -72.13475204444817f;
                    float p = exp2f(v0 - 72.13475204444817f);       // = exp(clamp(s)-50)
                    l_ += p;
                    pv[r] = p;
                }
                unsigned u[8];
                #pragma unroll
                for (int qq = 0; qq < 8; ++qq)
                    u[qq] = (unsigned)f2bf(pv[2 * qq]) | ((unsigned)f2bf(pv[2 * qq + 1]) << 16);
                #pragma unroll
                for (int hl = 0; hl < 2; ++hl) {    // two K=16 fragments per cb
                    unsigned a0 = u[hl * 4 + 0], a1 = u[hl * 4 + 1];
                    unsigned a2 = u[hl * 4 + 2], a3 = u[hl * 4 + 3];
                    unsigned x0 = half ? a0 : a2;
                    unsigned x1 = half ? a1 : a3;
                    unsigned y0 = (unsigned)__shfl_xor((int)x0, 32);
                    unsigned y1 = (unsigned)__shfl_xor((int)x1, 32);
                    union { unsigned uu[4]; bf16x8 v; } fr;
                    fr.uu[0] = half ? y0 : a0;
                    fr.uu[1] = half ? y1 : a1;
                    fr.uu[2] = half ? a2 : y0;
                    fr.uu[3] = half ? a3 : y1;
                    pf[cb * 2 + hl] = fr.v;
                }
            }

            // ---- O^T += V^T P^T ----
            #pragma unroll
            for (int kb = 0; kb < 4; ++kb) {
                #pragma unroll
                for (int cbd = 0; cbd < 4; ++cbd) {
                    const int d = cbd * 32 + l32;
                    bf16x8 vf = *(const bf16x8*)(Vl + d * 128 + (((kb * 2 + half) ^ (d & 7)) << 4));
                    o[cbd] = __builtin_amdgcn_mfma_f32_32x32x16_bf16(vf, pf[kb], o[cbd], 0, 0, 0);
                }
            }
        }
    }

    // ---- epilogue: combine halves of l, divide, transpose O^T -> O via LDS, coalesced store ----
    l_ += __shfl_xor(l_, 32);
    const float linv = 1.0f / l_;
    float* Og = Out + qbase;
    __syncthreads();                            // all compute done; smem free for reuse
    #pragma unroll
    for (int pass = 0; pass < 2; ++pass) {      // d halves: [0,64) then [64,128); buf = [m=128][68 floats]
        #pragma unroll
        for (int cb2 = 0; cb2 < 2; ++cb2) {
            const int cb = pass * 2 + cb2;
            #pragma unroll
            for (int q = 0; q < 4; ++q) {
                float4 vv = { o[cb][4 * q] * linv, o[cb][4 * q + 1] * linv,
                              o[cb][4 * q + 2] * linv, o[cb][4 * q + 3] * linv };
                *(float4*)(smem + (w * 32 + l32) * 272 + (cb2 * 32 + 8 * q + 4 * half) * 4) = vv;
            }
        }
        __syncthreads();
        #pragma unroll
        for (int rep = 0; rep < 8; ++rep) {
            int e = rep * 256 + t;
            int m = e >> 4, c = e & 15;
            float4 vv = *(const float4*)(smem + m * 272 + c * 16);
            *(float4*)(Og + (long)m * D_ + pass * 64 + c * 4) = vv;
        }
        __syncthreads();
    }
}

extern "C" void kernel_launch(void* const* d_in, const int* in_sizes, int n_in,
                              void* d_out, int out_size, void* d_ws, size_t ws_size,
                              hipStream_t stream) {
    const float* Q = (const float*)d_in[0];
    const float* K = (const float*)d_in[1];
    const float* V = (const float*)d_in[2];
    float* O = (float*)d_out;
    unsigned short* Kb = (unsigned short*)d_ws;                          // 16 MiB
    unsigned short* Vt = Kb + (long)BH_ * L_ * D_;                       // 16 MiB
    prepack<<<dim3(BH_, L_ / 64), dim3(256), 0, stream>>>(K, V, Kb, Vt);
    attn<<<dim3(BH_, NQT), dim3(256), 0, stream>>>(Q, Kb, Vt, O);
}